// Round 20
// baseline (160.152 us; speedup 1.0000x reference)
//
#include <hip/hip_runtime.h>
#include <hip/hip_bf16.h>

// dims
#define NB2 128
#define LQK 256
#define DIM 256
#define NH 8
#define CC 32

typedef __bf16 bf16x8 __attribute__((ext_vector_type(8)));
typedef __bf16 bf16x4 __attribute__((ext_vector_type(4)));
typedef __bf16 bf16x2 __attribute__((ext_vector_type(2)));
typedef float f32x4 __attribute__((ext_vector_type(4)));

#define MFMA16 __builtin_amdgcn_mfma_f32_16x16x32_bf16

// LDS tile row stride (bf16) for k_attn P: must stay ≡0 mod 8 elems (b128)
#define TP 72

#define NTOK ((size_t)NB2 * LQK * NH * CC)   // 8,388,608

// async global->LDS, 16B per lane; LDS dest is wave-uniform base + lane*16
static __device__ __forceinline__ void gload_lds16(const void* g, void* l) {
    __builtin_amdgcn_global_load_lds(
        (const __attribute__((address_space(1))) unsigned int*)g,
        (__attribute__((address_space(3))) unsigned int*)l,
        16, 0, 0);
}

// counted VMEM wait: leave N newest VMEM ops in flight
#define WAITV(N) do { asm volatile("s_waitcnt vmcnt(" #N ")" ::: "memory"); \
                      __builtin_amdgcn_sched_barrier(0); } while (0)
// raw barrier: drain LDS ops (cross-wave visibility) but NOT vmcnt
#define BARRIER_NOV() do { asm volatile("s_waitcnt lgkmcnt(0)" ::: "memory"); \
                           __builtin_amdgcn_s_barrier(); \
                           __builtin_amdgcn_sched_barrier(0); } while (0)

// ---------------- Kernel 0: fp32 -> bf16 (activations + weights) ----------
__global__ __launch_bounds__(256) void k_cvt(
    const float* __restrict__ qd, const float* __restrict__ kvd,
    const float* __restrict__ Wq, const float* __restrict__ Wk,
    const float* __restrict__ Wv, const float* __restrict__ Wg,
    const float* __restrict__ Wo,
    __bf16* __restrict__ qbf, __bf16* __restrict__ kvbf,
    __bf16* __restrict__ wBF)
{
    const int b = blockIdx.x;
    if (b < 8192) {
        size_t i = ((size_t)b * 256 + threadIdx.x) * 8;
        const float* src;
        __bf16* dst;
        if (i < NTOK) { src = qd + i; dst = qbf + i; }
        else          { src = kvd + (i - NTOK); dst = kvbf + (i - NTOK); }
        f32x4 a = *(const f32x4*)src;
        f32x4 c = *(const f32x4*)(src + 4);
        bf16x8 r;
        r[0] = (__bf16)a[0]; r[1] = (__bf16)a[1]; r[2] = (__bf16)a[2]; r[3] = (__bf16)a[3];
        r[4] = (__bf16)c[0]; r[5] = (__bf16)c[1]; r[6] = (__bf16)c[2]; r[7] = (__bf16)c[3];
        *(bf16x8*)dst = r;
    } else {
        int i = ((b - 8192) * 256 + threadIdx.x) * 4;
        int mat = i >> 16;
        int off = i & 65535;
        const float* src = (mat == 0) ? Wq : (mat == 1) ? Wk : (mat == 2) ? Wv
                          : (mat == 3) ? Wg : Wo;
        f32x4 v = *(const f32x4*)(src + off);
        __bf16* d = wBF + ((size_t)mat << 16) + off;
        d[0] = (__bf16)v[0]; d[1] = (__bf16)v[1]; d[2] = (__bf16)v[2]; d[3] = (__bf16)v[3];
    }
}

// ---------------- Kernel 1: QKVG projection (gload_lds GEMM) --------------
__global__ __launch_bounds__(256, 2) void k_proj(
    const __bf16* __restrict__ qbf, const __bf16* __restrict__ kvbf,
    const __bf16* __restrict__ wBF, const float* __restrict__ bg,
    __bf16* __restrict__ wsq, __bf16* __restrict__ wsk,
    __bf16* __restrict__ wsvT, __bf16* __restrict__ wsg)
{
    __shared__ __bf16 At[2][128 * 64];
    __shared__ __bf16 Bt[2][128 * 64];

    const int mb = blockIdx.x, nb = blockIdx.y;
    const int t = nb >> 1;                       // 0=q 1=k 2=v 3=g
    const __bf16* X = (t == 0 || t == 3) ? qbf : kvbf;
    const __bf16* W = wBF + ((size_t)t << 16) + (size_t)((nb & 1) * 128) * 256;

    const int tid = threadIdx.x;
    const int lane = tid & 63, w = tid >> 6;
    const int g = lane >> 4, c0 = lane & 15;
    const int mq = (w >> 1) * 64, nq = (w & 1) * 64;
    const int m0 = mb * 128;
    const int lrow = lane >> 3, lu = lane & 7;   // staging row-sub / unit

    auto stage = [&](int buf, int kt) {
#pragma unroll
        for (int i = 0; i < 4; i++) {
            const int rr = i * 32 + w * 8 + lrow;          // 0..127
            const int su = lu ^ (rr & 7);                  // src-unit swizzle
            gload_lds16(X + (size_t)(m0 + rr) * 256 + kt * 64 + su * 8,
                        &At[buf][(i * 4 + w) * 512]);
        }
#pragma unroll
        for (int i = 0; i < 4; i++) {
            const int rr = i * 32 + w * 8 + lrow;
            const int su = lu ^ (rr & 7);
            gload_lds16(W + (size_t)rr * 256 + kt * 64 + su * 8,
                        &Bt[buf][(i * 4 + w) * 512]);
        }
    };

    f32x4 acc[4][4] = {};
    stage(0, 0);
    __syncthreads();

#pragma unroll
    for (int kt = 0; kt < 4; kt++) {
        const int cur = kt & 1;
        if (kt < 3) stage(cur ^ 1, kt + 1);      // async; drains at barrier
#pragma unroll
        for (int ks = 0; ks < 2; ks++) {
            const int px = ((ks * 4 + g) ^ (c0 & 7)) * 8;  // phys unit offset
            bf16x8 af[4], bf_[4];
#pragma unroll
            for (int mi = 0; mi < 4; mi++)
                af[mi] = *(const bf16x8*)(&At[cur][(mq + mi * 16 + c0) * 64 + px]);
#pragma unroll
            for (int ni = 0; ni < 4; ni++)
                bf_[ni] = *(const bf16x8*)(&Bt[cur][(nq + ni * 16 + c0) * 64 + px]);
#pragma unroll
            for (int mi = 0; mi < 4; mi++)
#pragma unroll
                for (int ni = 0; ni < 4; ni++)
                    acc[mi][ni] = MFMA16(af[mi], bf_[ni], acc[mi][ni], 0, 0, 0);
        }
        __syncthreads();
    }

    // ---- epilogue ----
#pragma unroll
    for (int ni = 0; ni < 4; ni++) {
        const int nloc = (nb & 1) * 128 + nq + ni * 16 + c0;
        const int h = nloc >> 5, c = nloc & 31;
        const float bg_ = (t == 3) ? bg[nloc] : 0.0f;
#pragma unroll
        for (int mi = 0; mi < 4; mi++) {
            const int mbase = m0 + mq + mi * 16 + g * 4;
            const int b2 = mbase >> 8;
            if (t == 2) {
                bf16x4 pk;
#pragma unroll
                for (int reg = 0; reg < 4; reg++) pk[reg] = (__bf16)acc[mi][ni][reg];
                *(bf16x4*)(&wsvT[((size_t)(b2 * NH + h) * CC + c) * LQK + (mbase & 255)]) = pk;
            } else {
#pragma unroll
                for (int reg = 0; reg < 4; reg++) {
                    const int l = (mbase + reg) & 255;
                    float v = acc[mi][ni][reg];
                    size_t idx = ((size_t)(b2 * NH + h) * LQK + l) * CC + c;
                    if (t == 0)      wsq[idx] = (__bf16)(v * 0.17677669529663689f);
                    else if (t == 1) wsk[idx] = (__bf16)v;
                    else             wsg[idx] = (__bf16)(1.0f / (1.0f + __expf(-(v + bg_))));
                }
            }
        }
    }
}

// ---------------- Kernel 2: attention (counted-vmcnt, 3-buf bias) ---------
// grid 4096; XCD head-grouping. 4 phases of 16 q-rows x all 256 k.
// Bias staged TWO phases ahead into Bl[p%3]; barriers do NOT drain vmcnt
// (WAITV(4) leaves next stage in flight). loadregs issued BEFORE stage so
// their auto-waits also leave the stage outstanding. regs/op: mod-2 bufs.
__global__ __launch_bounds__(256, 2) void k_attn(
    const __bf16* __restrict__ wsq, const __bf16* __restrict__ wsk,
    const __bf16* __restrict__ wsvT, const __bf16* __restrict__ wsg,
    const float* __restrict__ bias, const float* __restrict__ nbb,
    __bf16* __restrict__ wswa)
{
    __shared__ float  Bl[3][16][256];     // 48 KB: 16 full bias rows, 3 bufs
    __shared__ __bf16 P[4][16][TP];       // 9 KB wave-private P
    __shared__ float  lsum[2][4][16];     // row-sum partials, dbuf
    __shared__ __bf16 op[2][4][16][40];   // 10 KB O k-partials bf16, dbuf

    const int tid = threadIdx.x;
    const int u0 = blockIdx.x;
    const int xcd = u0 & 7, slot = u0 >> 3;
    const int head = xcd + 8 * (slot >> 2);
    const int qt = slot & 3;
    const int b2 = head >> 3, h = head & 7;

    const int lane = tid & 63, w = tid >> 6;
    const int g = lane >> 4, kg = g * 8, c0 = lane & 15;

    const __bf16* qp = wsq + (size_t)(b2 * NH + h) * LQK * CC;
    const __bf16* kp = wsk + (size_t)(b2 * NH + h) * LQK * CC;
    const __bf16* vT = wsvT + (size_t)(b2 * NH + h) * CC * LQK;
    const __bf16* gR = wsg + (size_t)(b2 * NH + h) * LQK * CC;   // row-major
    const float* npb = nbb + (size_t)h * LQK * LQK;
    const float* bblk = bias + ((size_t)(b2 * NH + h) * LQK + qt * 64) * LQK;

    auto stage = [&](int buf, int p) {    // exactly 4 gload_lds per wave
#pragma unroll
        for (int i = 0; i < 4; i++) {
            const int row = w * 4 + i;                     // 0..15 in phase
            gload_lds16(bblk + (size_t)(p * 16 + row) * LQK + ((lane ^ row) * 4),
                        &Bl[buf][row][0]);
        }
    };

    // K/V fragments phase-invariant (wave k-slice fixed): load once.
    bf16x8 kf[4], vf[4];
#pragma unroll
    for (int j = 0; j < 4; j++)
        kf[j] = *(const bf16x8*)(kp + (size_t)(w * 64 + j * 16 + c0) * CC + kg);
#pragma unroll
    for (int kt2 = 0; kt2 < 2; kt2++)
#pragma unroll
        for (int vn = 0; vn < 2; vn++)
            vf[kt2 * 2 + vn] = *(const bf16x8*)(
                vT + (size_t)(vn * 16 + c0) * LQK + w * 64 + kt2 * 32 + kg);

    // reduce-step indexing (constant across phases)
    const int ridx = tid * 2;
    const int rqr = ridx >> 5;            // 0..15
    const int rcb = ridx & 31;            // even col base

    // per-phase register operands, double-buffered (exactly 6 VMEM loads)
    bf16x8 qfb[2];
    f32x4 nb4b[2][4];
    bf16x2 g2b[2];
    auto loadregs = [&](int buf, int p) {
        const int qglob = qt * 64 + p * 16 + c0;
        qfb[buf] = *(const bf16x8*)(qp + (size_t)qglob * CC + kg);
#pragma unroll
        for (int j = 0; j < 4; j++)
            nb4b[buf][j] = *(const f32x4*)(npb + (size_t)qglob * LQK + w * 64 + j * 16 + g * 4);
        const int qg = qt * 64 + p * 16 + rqr;
        g2b[buf] = *(const bf16x2*)(&gR[(size_t)qg * CC + rcb]);   // coalesced
    };

    auto compute = [&](int bl, int rb) {   // bl = Bl buffer (p%3), rb = p&1
        float csum = 0.0f;
#pragma unroll
        for (int j = 0; j < 4; j++) {
            f32x4 b4 = *(const f32x4*)(&Bl[bl][c0][(w * 16 + ((j * 4 + g) ^ c0)) * 4]);
            f32x4 cc;
#pragma unroll
            for (int r2 = 0; r2 < 4; r2++) cc[r2] = b4[r2] + nb4b[rb][j][r2];
            f32x4 s = MFMA16(kf[j], qfb[rb], cc, 0, 0, 0);
            bf16x4 pk;
#pragma unroll
            for (int r2 = 0; r2 < 4; r2++) {
                float e = __expf(s[r2]);      // no max-sub: |s| bounded ~20
                csum += e;
                pk[r2] = (__bf16)e;
            }
            *(bf16x4*)(&P[w][c0][j * 16 + g * 4]) = pk;
        }
        csum += __shfl_xor(csum, 16);
        csum += __shfl_xor(csum, 32);
        if (lane < 16) lsum[rb][w][lane] = csum;

        f32x4 o2[2] = {};
#pragma unroll
        for (int kt2 = 0; kt2 < 2; kt2++) {
            bf16x8 pa = *(const bf16x8*)(&P[w][c0][kt2 * 32 + kg]);
#pragma unroll
            for (int vn = 0; vn < 2; vn++)
                o2[vn] = MFMA16(pa, vf[kt2 * 2 + vn], o2[vn], 0, 0, 0);
        }
#pragma unroll
        for (int vn = 0; vn < 2; vn++)
#pragma unroll
            for (int r2 = 0; r2 < 4; r2++)
                op[rb][w][g * 4 + r2][vn * 16 + c0] = (__bf16)o2[vn][r2];
    };

    auto reduce_store = [&](int p, int pb) {   // pb = p&1
        const int qg = qt * 64 + p * 16 + rqr;
        const float li = 1.0f /
            (lsum[pb][0][rqr] + lsum[pb][1][rqr] + lsum[pb][2][rqr] + lsum[pb][3][rqr]);
        float v0 = (float)op[pb][0][rqr][rcb]     + (float)op[pb][1][rqr][rcb]
                 + (float)op[pb][2][rqr][rcb]     + (float)op[pb][3][rqr][rcb];
        float v1 = (float)op[pb][0][rqr][rcb + 1] + (float)op[pb][1][rqr][rcb + 1]
                 + (float)op[pb][2][rqr][rcb + 1] + (float)op[pb][3][rqr][rcb + 1];
        v0 *= li * (float)g2b[pb][0];
        v1 *= li * (float)g2b[pb][1];
        __bf16* dst = &wswa[((size_t)(b2 * LQK + qg)) * (NH * CC) + h * CC + rcb];
        dst[0] = (__bf16)v0;
        dst[1] = (__bf16)v1;
    };

    // ---- prologue: R0(6), S0(4), S1(4)  [outstanding 14] ----
    loadregs(0, 0);
    __builtin_amdgcn_sched_barrier(0);
    stage(0, 0);
    stage(1, 1);
    __builtin_amdgcn_sched_barrier(0);

    // p=0: Bl0, regs0
    WAITV(4);            // R0+S0 done; S1 floats
    BARRIER_NOV();
    loadregs(1, 1);      // R1 before S2 (FIFO)
    __builtin_amdgcn_sched_barrier(0);
    stage(2, 2);
    __builtin_amdgcn_sched_barrier(0);
    compute(0, 0);

    // p=1: Bl1, regs1
    WAITV(4);            // S1+R1 done; S2 floats
    BARRIER_NOV();
    reduce_store(0, 0);
    loadregs(0, 2);
    __builtin_amdgcn_sched_barrier(0);
    stage(0, 3);         // buf0: phase-0 readers done at barrier
    __builtin_amdgcn_sched_barrier(0);
    compute(1, 1);

    // p=2: Bl2, regs0
    WAITV(4);            // S2+R2 done; S3 floats
    BARRIER_NOV();
    reduce_store(1, 1);
    loadregs(1, 3);
    __builtin_amdgcn_sched_barrier(0);
    compute(2, 0);

    // p=3: Bl0, regs1
    WAITV(0);            // S3+R3 done
    BARRIER_NOV();
    reduce_store(2, 0);
    compute(0, 1);
    __syncthreads();
    reduce_store(3, 1);
}

// ---------------- Kernel 3: output projection (gload_lds GEMM) ------------
__global__ __launch_bounds__(256, 2) void k_out(
    const __bf16* __restrict__ wa, const __bf16* __restrict__ wBF,
    const float* __restrict__ bo, float* __restrict__ out)
{
    __shared__ __bf16 At[2][128 * 64];
    __shared__ __bf16 Bt[2][128 * 64];

    const int mb = blockIdx.x, nb = blockIdx.y;
    const __bf16* W = wBF + ((size_t)4 << 16) + (size_t)(nb * 128) * 256;

    const int tid = threadIdx.x;
    const int lane = tid & 63, w = tid >> 6;
    const int g = lane >> 4, c0 = lane & 15;
    const int mq = (w >> 1) * 64, nq = (w & 1) * 64;
    const int m0 = mb * 128;
    const int lrow = lane >> 3, lu = lane & 7;

    auto stage = [&](int buf, int kt) {
#pragma unroll
        for (int i = 0; i < 4; i++) {
            const int rr = i * 32 + w * 8 + lrow;
            const int su = lu ^ (rr & 7);
            gload_lds16(wa + (size_t)(m0 + rr) * 256 + kt * 64 + su * 8,
                        &At[buf][(i * 4 + w) * 512]);
        }
#pragma unroll
        for (int i = 0; i < 4; i++) {
            const int rr = i * 32 + w * 8 + lrow;
            const int su = lu ^ (rr & 7);
            gload_lds16(W + (size_t)rr * 256 + kt * 64 + su * 8,
                        &Bt[buf][(i * 4 + w) * 512]);
        }
    };

    f32x4 acc[4][4] = {};
    stage(0, 0);
    __syncthreads();

#pragma unroll
    for (int kt = 0; kt < 4; kt++) {
        const int cur = kt & 1;
        if (kt < 3) stage(cur ^ 1, kt + 1);
#pragma unroll
        for (int ks = 0; ks < 2; ks++) {
            const int px = ((ks * 4 + g) ^ (c0 & 7)) * 8;
            bf16x8 af[4], bf_[4];
#pragma unroll
            for (int mi = 0; mi < 4; mi++)
                af[mi] = *(const bf16x8*)(&At[cur][(mq + mi * 16 + c0) * 64 + px]);
#pragma unroll
            for (int ni = 0; ni < 4; ni++)
                bf_[ni] = *(const bf16x8*)(&Bt[cur][(nq + ni * 16 + c0) * 64 + px]);
#pragma unroll
            for (int mi = 0; mi < 4; mi++)
#pragma unroll
                for (int ni = 0; ni < 4; ni++)
                    acc[mi][ni] = MFMA16(af[mi], bf_[ni], acc[mi][ni], 0, 0, 0);
        }
        __syncthreads();
    }

#pragma unroll
    for (int ni = 0; ni < 4; ni++) {
        const int n = nb * 128 + nq + ni * 16 + c0;
        const float bo_ = bo[n];
#pragma unroll
        for (int mi = 0; mi < 4; mi++) {
            const int mbase = m0 + mq + mi * 16 + g * 4;
#pragma unroll
            for (int reg = 0; reg < 4; reg++)
                out[(size_t)(mbase + reg) * 256 + n] = acc[mi][ni][reg] + bo_;
        }
    }
}

// ---------------- launcher ------------------------------------------------
extern "C" void kernel_launch(void* const* d_in, const int* in_sizes, int n_in,
                              void* d_out, int out_size, void* d_ws, size_t ws_size,
                              hipStream_t stream) {
    const float* qd  = (const float*)d_in[0];
    const float* kvd = (const float*)d_in[1];
    const float* bias = (const float*)d_in[2];
    const float* nbb = (const float*)d_in[3];
    const float* Wq = (const float*)d_in[4];
    const float* Wk = (const float*)d_in[5];
    const float* Wv = (const float*)d_in[6];
    const float* Wg = (const float*)d_in[7];
    const float* bg = (const float*)d_in[8];
    const float* Wo = (const float*)d_in[9];
    const float* bo = (const float*)d_in[10];
    float* out = (float*)d_out;

    __bf16* ws = (__bf16*)d_ws;
    __bf16* wsq  = ws;
    __bf16* wsk  = wsq + NTOK;
    __bf16* wsvT = wsk + NTOK;
    __bf16* wsg  = wsvT + NTOK;
    __bf16* wBF  = wsg + NTOK;             // 5 * 65536 bf16 weights
    __bf16* qbf  = wBF + 5 * 65536;        // activations bf16 (dead after k_proj)
    __bf16* kvbf = qbf + NTOK;
    __bf16* wswa = qbf;                    // alias: written by k_attn after k_proj

    k_cvt<<<dim3(8512), 256, 0, stream>>>(qd, kvd, Wq, Wk, Wv, Wg, Wo,
                                          qbf, kvbf, wBF);
    k_proj<<<dim3(256, 8), 256, 0, stream>>>(qbf, kvbf, wBF, bg,
                                             wsq, wsk, wsvT, wsg);
    k_attn<<<dim3(4096), 256, 0, stream>>>(wsq, wsk, wsvT, wsg, bias, nbb, wswa);
    k_out<<<dim3(256, 2), 256, 0, stream>>>(wswa, wBF, bo, out);
}

// Round 21
// 155.860 us; speedup vs baseline: 1.0275x; 1.0275x over previous
//
#include <hip/hip_runtime.h>
#include <hip/hip_bf16.h>

// dims
#define NB2 128
#define LQK 256
#define DIM 256
#define NH 8
#define CC 32

typedef __bf16 bf16x8 __attribute__((ext_vector_type(8)));
typedef __bf16 bf16x4 __attribute__((ext_vector_type(4)));
typedef __bf16 bf16x2 __attribute__((ext_vector_type(2)));
typedef float f32x4 __attribute__((ext_vector_type(4)));

#define MFMA16 __builtin_amdgcn_mfma_f32_16x16x32_bf16

// LDS tile row stride (bf16) for k_attn P: must stay ≡0 mod 8 elems (b128)
#define TP 72

#define NTOK ((size_t)NB2 * LQK * NH * CC)   // 8,388,608

// async global->LDS, 16B per lane; LDS dest is wave-uniform base + lane*16
static __device__ __forceinline__ void gload_lds16(const void* g, void* l) {
    __builtin_amdgcn_global_load_lds(
        (const __attribute__((address_space(1))) unsigned int*)g,
        (__attribute__((address_space(3))) unsigned int*)l,
        16, 0, 0);
}

// ---------------- Kernel 0: fp32 -> bf16 (activations + weights) ----------
__global__ __launch_bounds__(256) void k_cvt(
    const float* __restrict__ qd, const float* __restrict__ kvd,
    const float* __restrict__ Wq, const float* __restrict__ Wk,
    const float* __restrict__ Wv, const float* __restrict__ Wg,
    const float* __restrict__ Wo,
    __bf16* __restrict__ qbf, __bf16* __restrict__ kvbf,
    __bf16* __restrict__ wBF)
{
    const int b = blockIdx.x;
    if (b < 8192) {
        size_t i = ((size_t)b * 256 + threadIdx.x) * 8;
        const float* src;
        __bf16* dst;
        if (i < NTOK) { src = qd + i; dst = qbf + i; }
        else          { src = kvd + (i - NTOK); dst = kvbf + (i - NTOK); }
        f32x4 a = *(const f32x4*)src;
        f32x4 c = *(const f32x4*)(src + 4);
        bf16x8 r;
        r[0] = (__bf16)a[0]; r[1] = (__bf16)a[1]; r[2] = (__bf16)a[2]; r[3] = (__bf16)a[3];
        r[4] = (__bf16)c[0]; r[5] = (__bf16)c[1]; r[6] = (__bf16)c[2]; r[7] = (__bf16)c[3];
        *(bf16x8*)dst = r;
    } else {
        int i = ((b - 8192) * 256 + threadIdx.x) * 4;
        int mat = i >> 16;
        int off = i & 65535;
        const float* src = (mat == 0) ? Wq : (mat == 1) ? Wk : (mat == 2) ? Wv
                          : (mat == 3) ? Wg : Wo;
        f32x4 v = *(const f32x4*)(src + off);
        __bf16* d = wBF + ((size_t)mat << 16) + off;
        d[0] = (__bf16)v[0]; d[1] = (__bf16)v[1]; d[2] = (__bf16)v[2]; d[3] = (__bf16)v[3];
    }
}

// ---------------- Kernel 1: QKVG projection (gload_lds GEMM) --------------
__global__ __launch_bounds__(256, 2) void k_proj(
    const __bf16* __restrict__ qbf, const __bf16* __restrict__ kvbf,
    const __bf16* __restrict__ wBF, const float* __restrict__ bg,
    __bf16* __restrict__ wsq, __bf16* __restrict__ wsk,
    __bf16* __restrict__ wsvT, __bf16* __restrict__ wsg)
{
    __shared__ __bf16 At[2][128 * 64];
    __shared__ __bf16 Bt[2][128 * 64];

    const int mb = blockIdx.x, nb = blockIdx.y;
    const int t = nb >> 1;                       // 0=q 1=k 2=v 3=g
    const __bf16* X = (t == 0 || t == 3) ? qbf : kvbf;
    const __bf16* W = wBF + ((size_t)t << 16) + (size_t)((nb & 1) * 128) * 256;

    const int tid = threadIdx.x;
    const int lane = tid & 63, w = tid >> 6;
    const int g = lane >> 4, c0 = lane & 15;
    const int mq = (w >> 1) * 64, nq = (w & 1) * 64;
    const int m0 = mb * 128;
    const int lrow = lane >> 3, lu = lane & 7;   // staging row-sub / unit

    auto stage = [&](int buf, int kt) {
#pragma unroll
        for (int i = 0; i < 4; i++) {
            const int rr = i * 32 + w * 8 + lrow;          // 0..127
            const int su = lu ^ (rr & 7);                  // src-unit swizzle
            gload_lds16(X + (size_t)(m0 + rr) * 256 + kt * 64 + su * 8,
                        &At[buf][(i * 4 + w) * 512]);
        }
#pragma unroll
        for (int i = 0; i < 4; i++) {
            const int rr = i * 32 + w * 8 + lrow;
            const int su = lu ^ (rr & 7);
            gload_lds16(W + (size_t)rr * 256 + kt * 64 + su * 8,
                        &Bt[buf][(i * 4 + w) * 512]);
        }
    };

    f32x4 acc[4][4] = {};
    stage(0, 0);
    __syncthreads();

#pragma unroll
    for (int kt = 0; kt < 4; kt++) {
        const int cur = kt & 1;
        if (kt < 3) stage(cur ^ 1, kt + 1);      // async; drains at barrier
#pragma unroll
        for (int ks = 0; ks < 2; ks++) {
            const int px = ((ks * 4 + g) ^ (c0 & 7)) * 8;  // phys unit offset
            bf16x8 af[4], bf_[4];
#pragma unroll
            for (int mi = 0; mi < 4; mi++)
                af[mi] = *(const bf16x8*)(&At[cur][(mq + mi * 16 + c0) * 64 + px]);
#pragma unroll
            for (int ni = 0; ni < 4; ni++)
                bf_[ni] = *(const bf16x8*)(&Bt[cur][(nq + ni * 16 + c0) * 64 + px]);
#pragma unroll
            for (int mi = 0; mi < 4; mi++)
#pragma unroll
                for (int ni = 0; ni < 4; ni++)
                    acc[mi][ni] = MFMA16(af[mi], bf_[ni], acc[mi][ni], 0, 0, 0);
        }
        __syncthreads();
    }

    // ---- epilogue ----
#pragma unroll
    for (int ni = 0; ni < 4; ni++) {
        const int nloc = (nb & 1) * 128 + nq + ni * 16 + c0;
        const int h = nloc >> 5, c = nloc & 31;
        const float bg_ = (t == 3) ? bg[nloc] : 0.0f;
#pragma unroll
        for (int mi = 0; mi < 4; mi++) {
            const int mbase = m0 + mq + mi * 16 + g * 4;
            const int b2 = mbase >> 8;
            if (t == 2) {
                bf16x4 pk;
#pragma unroll
                for (int reg = 0; reg < 4; reg++) pk[reg] = (__bf16)acc[mi][ni][reg];
                *(bf16x4*)(&wsvT[((size_t)(b2 * NH + h) * CC + c) * LQK + (mbase & 255)]) = pk;
            } else {
#pragma unroll
                for (int reg = 0; reg < 4; reg++) {
                    const int l = (mbase + reg) & 255;
                    float v = acc[mi][ni][reg];
                    size_t idx = ((size_t)(b2 * NH + h) * LQK + l) * CC + c;
                    if (t == 0)      wsq[idx] = (__bf16)(v * 0.17677669529663689f);
                    else if (t == 1) wsk[idx] = (__bf16)v;
                    else             wsg[idx] = (__bf16)(1.0f / (1.0f + __expf(-(v + bg_))));
                }
            }
        }
    }
}

// ---------------- Kernel 2: attention (q-phased; 1 barrier/phase) ---------
// grid 4096; XCD head-grouping. 4 phases of 16 q-rows x all 256 k.
// Phase p (buffer cur=p&1): [reduce(p-1) from buffers ~cur]
// [stage(p+1)+loadregs(p+1) into ~cur] [compute(buffer cur)] [barrier].
// compute() takes the BUFFER index (p&1), not the phase number.
__global__ __launch_bounds__(256, 3) void k_attn(
    const __bf16* __restrict__ wsq, const __bf16* __restrict__ wsk,
    const __bf16* __restrict__ wsvT, const __bf16* __restrict__ wsg,
    const float* __restrict__ bias, const float* __restrict__ nbb,
    __bf16* __restrict__ wswa)
{
    __shared__ float  Bl[2][16][256];     // 32 KB: 16 full bias rows, dbuf
    __shared__ __bf16 P[4][16][TP];       // 9 KB wave-private P
    __shared__ float  lsum[2][4][16];     // row-sum partials, dbuf
    __shared__ __bf16 op[2][4][16][40];   // 10 KB O k-partials bf16, dbuf

    const int tid = threadIdx.x;
    const int u0 = blockIdx.x;
    const int xcd = u0 & 7, slot = u0 >> 3;
    const int head = xcd + 8 * (slot >> 2);
    const int qt = slot & 3;
    const int b2 = head >> 3, h = head & 7;

    const int lane = tid & 63, w = tid >> 6;
    const int g = lane >> 4, kg = g * 8, c0 = lane & 15;

    const __bf16* qp = wsq + (size_t)(b2 * NH + h) * LQK * CC;
    const __bf16* kp = wsk + (size_t)(b2 * NH + h) * LQK * CC;
    const __bf16* vT = wsvT + (size_t)(b2 * NH + h) * CC * LQK;
    const __bf16* gR = wsg + (size_t)(b2 * NH + h) * LQK * CC;   // row-major
    const float* npb = nbb + (size_t)h * LQK * LQK;
    const float* bblk = bias + ((size_t)(b2 * NH + h) * LQK + qt * 64) * LQK;

    auto stage = [&](int buf, int p) {
#pragma unroll
        for (int i = 0; i < 4; i++) {
            const int row = w * 4 + i;                     // 0..15 in phase
            gload_lds16(bblk + (size_t)(p * 16 + row) * LQK + ((lane ^ row) * 4),
                        &Bl[buf][row][0]);
        }
    };

    // K/V fragments phase-invariant (wave's k-slice fixed): load once.
    bf16x8 kf[4], vf[4];
#pragma unroll
    for (int j = 0; j < 4; j++)
        kf[j] = *(const bf16x8*)(kp + (size_t)(w * 64 + j * 16 + c0) * CC + kg);
#pragma unroll
    for (int kt2 = 0; kt2 < 2; kt2++)
#pragma unroll
        for (int vn = 0; vn < 2; vn++)
            vf[kt2 * 2 + vn] = *(const bf16x8*)(
                vT + (size_t)(vn * 16 + c0) * LQK + w * 64 + kt2 * 32 + kg);

    // reduce-step indexing (constant across phases)
    const int ridx = tid * 2;
    const int rqr = ridx >> 5;            // 0..15
    const int rcb = ridx & 31;            // even col base

    // per-phase register operands, double-buffered
    bf16x8 qfb[2];
    f32x4 nb4b[2][4];
    bf16x2 g2b[2];
    auto loadregs = [&](int buf, int p) {
        const int qglob = qt * 64 + p * 16 + c0;
        qfb[buf] = *(const bf16x8*)(qp + (size_t)qglob * CC + kg);
#pragma unroll
        for (int j = 0; j < 4; j++)
            nb4b[buf][j] = *(const f32x4*)(npb + (size_t)qglob * LQK + w * 64 + j * 16 + g * 4);
        const int qg = qt * 64 + p * 16 + rqr;
        g2b[buf] = *(const bf16x2*)(&gR[(size_t)qg * CC + rcb]);   // coalesced
    };

    auto compute = [&](int cur) {          // cur = BUFFER index = p&1
        float csum = 0.0f;
#pragma unroll
        for (int j = 0; j < 4; j++) {
            f32x4 b4 = *(const f32x4*)(&Bl[cur][c0][(w * 16 + ((j * 4 + g) ^ c0)) * 4]);
            f32x4 cc;
#pragma unroll
            for (int r2 = 0; r2 < 4; r2++) cc[r2] = b4[r2] + nb4b[cur][j][r2];
            f32x4 s = MFMA16(kf[j], qfb[cur], cc, 0, 0, 0);
            bf16x4 pk;
#pragma unroll
            for (int r2 = 0; r2 < 4; r2++) {
                float e = __expf(s[r2]);      // no max-sub: |s| bounded ~20
                csum += e;
                pk[r2] = (__bf16)e;
            }
            *(bf16x4*)(&P[w][c0][j * 16 + g * 4]) = pk;
        }
        csum += __shfl_xor(csum, 16);
        csum += __shfl_xor(csum, 32);
        if (lane < 16) lsum[cur][w][lane] = csum;

        f32x4 o2[2] = {};
#pragma unroll
        for (int kt2 = 0; kt2 < 2; kt2++) {
            bf16x8 pa = *(const bf16x8*)(&P[w][c0][kt2 * 32 + kg]);
#pragma unroll
            for (int vn = 0; vn < 2; vn++)
                o2[vn] = MFMA16(pa, vf[kt2 * 2 + vn], o2[vn], 0, 0, 0);
        }
#pragma unroll
        for (int vn = 0; vn < 2; vn++)
#pragma unroll
            for (int r2 = 0; r2 < 4; r2++)
                op[cur][w][g * 4 + r2][vn * 16 + c0] = (__bf16)o2[vn][r2];
    };

    auto reduce_store = [&](int p, int pb) {
        const int qg = qt * 64 + p * 16 + rqr;
        const float li = 1.0f /
            (lsum[pb][0][rqr] + lsum[pb][1][rqr] + lsum[pb][2][rqr] + lsum[pb][3][rqr]);
        float v0 = (float)op[pb][0][rqr][rcb]     + (float)op[pb][1][rqr][rcb]
                 + (float)op[pb][2][rqr][rcb]     + (float)op[pb][3][rqr][rcb];
        float v1 = (float)op[pb][0][rqr][rcb + 1] + (float)op[pb][1][rqr][rcb + 1]
                 + (float)op[pb][2][rqr][rcb + 1] + (float)op[pb][3][rqr][rcb + 1];
        v0 *= li * (float)g2b[pb][0];
        v1 *= li * (float)g2b[pb][1];
        __bf16* dst = &wswa[((size_t)(b2 * LQK + qg)) * (NH * CC) + h * CC + rcb];
        dst[0] = (__bf16)v0;
        dst[1] = (__bf16)v1;
    };

    stage(0, 0);
    loadregs(0, 0);
    __syncthreads();                      // drains stage0 + regs0

    // p=0 (buffer 0)
    stage(1, 1); loadregs(1, 1);
    __builtin_amdgcn_sched_barrier(0);
    compute(0);
    __syncthreads();
    // p=1 (buffer 1)
    reduce_store(0, 0);
    stage(0, 2); loadregs(0, 2);
    __builtin_amdgcn_sched_barrier(0);
    compute(1);
    __syncthreads();
    // p=2 (buffer 0)
    reduce_store(1, 1);
    stage(1, 3); loadregs(1, 3);
    __builtin_amdgcn_sched_barrier(0);
    compute(0);
    __syncthreads();
    // p=3 (buffer 1)
    reduce_store(2, 0);
    compute(1);
    __syncthreads();
    reduce_store(3, 1);
}

// ---------------- Kernel 3: output projection (gload_lds GEMM) ------------
__global__ __launch_bounds__(256, 2) void k_out(
    const __bf16* __restrict__ wa, const __bf16* __restrict__ wBF,
    const float* __restrict__ bo, float* __restrict__ out)
{
    __shared__ __bf16 At[2][128 * 64];
    __shared__ __bf16 Bt[2][128 * 64];

    const int mb = blockIdx.x, nb = blockIdx.y;
    const __bf16* W = wBF + ((size_t)4 << 16) + (size_t)(nb * 128) * 256;

    const int tid = threadIdx.x;
    const int lane = tid & 63, w = tid >> 6;
    const int g = lane >> 4, c0 = lane & 15;
    const int mq = (w >> 1) * 64, nq = (w & 1) * 64;
    const int m0 = mb * 128;
    const int lrow = lane >> 3, lu = lane & 7;

    auto stage = [&](int buf, int kt) {
#pragma unroll
        for (int i = 0; i < 4; i++) {
            const int rr = i * 32 + w * 8 + lrow;
            const int su = lu ^ (rr & 7);
            gload_lds16(wa + (size_t)(m0 + rr) * 256 + kt * 64 + su * 8,
                        &At[buf][(i * 4 + w) * 512]);
        }
#pragma unroll
        for (int i = 0; i < 4; i++) {
            const int rr = i * 32 + w * 8 + lrow;
            const int su = lu ^ (rr & 7);
            gload_lds16(W + (size_t)rr * 256 + kt * 64 + su * 8,
                        &Bt[buf][(i * 4 + w) * 512]);
        }
    };

    f32x4 acc[4][4] = {};
    stage(0, 0);
    __syncthreads();

#pragma unroll
    for (int kt = 0; kt < 4; kt++) {
        const int cur = kt & 1;
        if (kt < 3) stage(cur ^ 1, kt + 1);
#pragma unroll
        for (int ks = 0; ks < 2; ks++) {
            const int px = ((ks * 4 + g) ^ (c0 & 7)) * 8;
            bf16x8 af[4], bf_[4];
#pragma unroll
            for (int mi = 0; mi < 4; mi++)
                af[mi] = *(const bf16x8*)(&At[cur][(mq + mi * 16 + c0) * 64 + px]);
#pragma unroll
            for (int ni = 0; ni < 4; ni++)
                bf_[ni] = *(const bf16x8*)(&Bt[cur][(nq + ni * 16 + c0) * 64 + px]);
#pragma unroll
            for (int mi = 0; mi < 4; mi++)
#pragma unroll
                for (int ni = 0; ni < 4; ni++)
                    acc[mi][ni] = MFMA16(af[mi], bf_[ni], acc[mi][ni], 0, 0, 0);
        }
        __syncthreads();
    }

#pragma unroll
    for (int ni = 0; ni < 4; ni++) {
        const int n = nb * 128 + nq + ni * 16 + c0;
        const float bo_ = bo[n];
#pragma unroll
        for (int mi = 0; mi < 4; mi++) {
            const int mbase = m0 + mq + mi * 16 + g * 4;
#pragma unroll
            for (int reg = 0; reg < 4; reg++)
                out[(size_t)(mbase + reg) * 256 + n] = acc[mi][ni][reg] + bo_;
        }
    }
}

// ---------------- launcher ------------------------------------------------
extern "C" void kernel_launch(void* const* d_in, const int* in_sizes, int n_in,
                              void* d_out, int out_size, void* d_ws, size_t ws_size,
                              hipStream_t stream) {
    const float* qd  = (const float*)d_in[0];
    const float* kvd = (const float*)d_in[1];
    const float* bias = (const float*)d_in[2];
    const float* nbb = (const float*)d_in[3];
    const float* Wq = (const float*)d_in[4];
    const float* Wk = (const float*)d_in[5];
    const float* Wv = (const float*)d_in[6];
    const float* Wg = (const float*)d_in[7];
    const float* bg = (const float*)d_in[8];
    const float* Wo = (const float*)d_in[9];
    const float* bo = (const float*)d_in[10];
    float* out = (float*)d_out;

    __bf16* ws = (__bf16*)d_ws;
    __bf16* wsq  = ws;
    __bf16* wsk  = wsq + NTOK;
    __bf16* wsvT = wsk + NTOK;
    __bf16* wsg  = wsvT + NTOK;
    __bf16* wBF  = wsg + NTOK;             // 5 * 65536 bf16 weights
    __bf16* qbf  = wBF + 5 * 65536;        // activations bf16 (dead after k_proj)
    __bf16* kvbf = qbf + NTOK;
    __bf16* wswa = qbf;                    // alias: written by k_attn after k_proj

    k_cvt<<<dim3(8512), 256, 0, stream>>>(qd, kvd, Wq, Wk, Wv, Wg, Wo,
                                          qbf, kvbf, wBF);
    k_proj<<<dim3(256, 8), 256, 0, stream>>>(qbf, kvbf, wBF, bg,
                                             wsq, wsk, wsvT, wsg);
    k_attn<<<dim3(4096), 256, 0, stream>>>(wsq, wsk, wsvT, wsg, bias, nbb, wswa);
    k_out<<<dim3(256, 2), 256, 0, stream>>>(wswa, wBF, bo, out);
}